// Round 11
// baseline (465.065 us; speedup 1.0000x reference)
//
#include <hip/hip_runtime.h>
#include <hip/hip_bf16.h>
#include <cstdio>
#include <cstdint>

#define B_    2
#define S_    2048
#define H_    32
#define KVH_  8
#define D_    128
#define HID_  4096
#define WIN_  512
#define NROW_ (B_*S_)          // 4096 rows for projection GEMMs
#define NKV_  2048             // fused k|v output width
#define SCALE_ 0.08838834764831845f          // 128^-0.5
#define SL2E_  0.12751744932973953f          // SCALE_ * log2(e)

typedef __attribute__((ext_vector_type(8))) __bf16 bf16x8;
typedef __attribute__((ext_vector_type(4))) __bf16 bf16x4;
typedef __attribute__((ext_vector_type(4))) float  f32x4;

#define GAS __attribute__((address_space(1)))
#define LAS __attribute__((address_space(3)))

// ------------------------------------------------- merged prep: cvt hidden + 4 weight transposes
__global__ __launch_bounds__(256) void prep_all(const float* __restrict__ hidden,
                                                const float* __restrict__ wq,
                                                const float* __restrict__ wk,
                                                const float* __restrict__ wv,
                                                const float* __restrict__ wo,
                                                __hip_bfloat16* __restrict__ hb,
                                                __hip_bfloat16* __restrict__ wqT,
                                                __hip_bfloat16* __restrict__ wkvT,
                                                __hip_bfloat16* __restrict__ woT) {
    __shared__ float t[32][33];
    const int bid = blockIdx.x;
    if (bid < 16384) {
        const int i = (bid * 256 + threadIdx.x) * 4;
        float4 v = *(const float4*)(hidden + i);
        __hip_bfloat162 a, b;
        a.x = __float2bfloat16(v.x); a.y = __float2bfloat16(v.y);
        b.x = __float2bfloat16(v.z); b.y = __float2bfloat16(v.w);
        *(__hip_bfloat162*)(hb + i)     = a;
        *(__hip_bfloat162*)(hb + i + 2) = b;
        return;
    }
    const int tx = threadIdx.x & 31, ty = threadIdx.x >> 5;
    const int id = bid - 16384;
    const float* src; __hip_bfloat16* dst; int C, idx;   // R always 4096
    if (id < 16384)      { src = wq; dst = wqT;  C = 4096; idx = id; }
    else if (id < 20480) { src = wk; dst = wkvT; C = 1024; idx = id - 16384; }
    else if (id < 24576) { src = wv; dst = wkvT + (size_t)1024*HID_; C = 1024; idx = id - 20480; }
    else                 { src = wo; dst = woT;  C = 4096; idx = id - 24576; }
    const int ctiles = C >> 5;
    const int c0 = (idx % ctiles) * 32, r0 = (idx / ctiles) * 32;
    #pragma unroll
    for (int i = 0; i < 4; ++i)
        t[ty + 8*i][tx] = src[(size_t)(r0 + ty + 8*i) * C + c0 + tx];
    __syncthreads();
    #pragma unroll
    for (int i = 0; i < 4; ++i)
        dst[(size_t)(c0 + ty + 8*i) * HID_ + r0 + tx] = __float2bfloat16(t[tx][ty + 8*i]);
}

// ------------------------------------------------- GEMM 256xBN, BK=32, ring-4, 1-barrier/tile
// R11 change: K-loop is UNPINNED — no sched_barrier/lgkm/setprio inside the tile.  The
// compiler emits its native fine-grained lgkmcnt(N) interleave of ds_read and MFMA (G7/m97),
// creating per-wave read/MFMA ping-pong and cross-wave LDS<->MFMA pipe overlap (m141 lesson:
// order-pinning defeats this).  Sync skeleton unchanged from R9/R10 (hazard-audited):
// ring-4 slots, 3-tile stage lead, trailing vmcnt(2L)+s_barrier per tile confirms slot t+1
// before tile t+1's reads; WAR on slot recycling protected because every ds_read feeds an
// MFMA before the end barrier (compiler auto-drains lgkm to 0 by the last MFMA).
template <int FN, int OMODE>
__global__ __launch_bounds__(512, 2) void gemm_t(const __hip_bfloat16* __restrict__ A,
                                                 const __hip_bfloat16* __restrict__ Bt,
                                                 void* __restrict__ Cv, void* __restrict__ C2,
                                                 int M, int N, int K, int nbx) {
    constexpr int BN   = FN * 64;
    constexpr int BLD  = BN / 128;                      // B stage loads/thread/tile (2 or 1)
    constexpr int SLOT = (256 + BN) * 32;               // elems per ring slot (A then B)
    __shared__ __align__(16) __hip_bfloat16 L[4 * SLOT];
    const int tid  = threadIdx.x;
    const int lane = tid & 63, w = tid >> 6;
    const int wm = w >> 2, wn = w & 3;                  // 2 x 4 wave grid
    const int lc = lane & 15, lg = lane >> 4;
    const int nwg = gridDim.x, cpx = nwg >> 3;
    const int bid = blockIdx.x;
    const int swz = (bid & 7) * cpx + (bid >> 3);
    const int by = swz / nbx, bx = swz - by * nbx;
    const size_t row0 = (size_t)by * 256, col0 = (size_t)bx * BN;
    const int nt = K >> 5;                              // BK = 32

    const int srow = tid >> 2;
    const int spc  = tid & 3;
    const int slx  = spc ^ ((srow >> 1) & 3);
    const __hip_bfloat16* Ab = A  + row0 * K;
    const __hip_bfloat16* Bb = Bt + col0 * K;

#define STGA(tile_) do {                                                                   \
    const int ss_ = (tile_) & 3;                                                           \
    const int kt_ = ((tile_) < nt) ? (tile_) : (nt - 1);                                   \
    _Pragma("unroll")                                                                      \
    for (int rh_ = 0; rh_ < 2; ++rh_)                                                      \
        __builtin_amdgcn_global_load_lds(                                                  \
            (const GAS void*)(Ab + (size_t)(rh_*128 + srow) * K + kt_*32 + slx*8),         \
            (LAS void*)&L[ss_*SLOT + rh_*4096 + w*512], 16, 0, 0);                         \
} while (0)

#define STGB(tile_) do {                                                                   \
    const int ss_ = (tile_) & 3;                                                           \
    const int kt_ = ((tile_) < nt) ? (tile_) : (nt - 1);                                   \
    _Pragma("unroll")                                                                      \
    for (int bh_ = 0; bh_ < BLD; ++bh_)                                                    \
        __builtin_amdgcn_global_load_lds(                                                  \
            (const GAS void*)(Bb + (size_t)(bh_*128 + srow) * K + kt_*32 + slx*8),         \
            (LAS void*)&L[ss_*SLOT + 8192 + bh_*4096 + w*512], 16, 0, 0);                  \
} while (0)

#define VMW2L() do {                                                                       \
    if constexpr (FN == 4) asm volatile("s_waitcnt vmcnt(8)" ::: "memory");                \
    else                   asm volatile("s_waitcnt vmcnt(6)" ::: "memory");                \
} while (0)

    f32x4 acc[2][4][FN] = {};
    bf16x8 afr0[4], afr1[4], bfr[FN];

    STGA(0); STGB(0); STGA(1); STGB(1); STGA(2); STGB(2);
    VMW2L();
    asm volatile("s_barrier" ::: "memory");

    for (int t = 0; t < nt; ++t) {
        const int s_ = t & 3;
        // ---- reads: plain loads, no pins — compiler interleaves lgkm waits with MFMAs
        #pragma unroll
        for (int fn = 0; fn < FN; ++fn) {
            const int rB = wn*(FN*16) + fn*16 + lc;
            bfr[fn] = *(const bf16x8*)&L[s_*SLOT + 8192 + rB*32 + ((lg ^ ((rB >> 1) & 3)) * 8)];
        }
        #pragma unroll
        for (int fm = 0; fm < 4; ++fm) {
            const int rA = wm*128 + fm*16 + lc;
            afr0[fm] = *(const bf16x8*)&L[s_*SLOT + rA*32 + ((lg ^ ((rA >> 1) & 3)) * 8)];
        }
        #pragma unroll
        for (int fm = 0; fm < 4; ++fm) {
            const int rA = wm*128 + 64 + fm*16 + lc;
            afr1[fm] = *(const bf16x8*)&L[s_*SLOT + rA*32 + ((lg ^ ((rA >> 1) & 3)) * 8)];
        }
        STGA(t + 3);
        STGB(t + 3);
        // ---- MFMAs: plain, dependency-ordered; compiler schedules reads/waits between them
        #pragma unroll
        for (int fm = 0; fm < 4; ++fm)
            #pragma unroll
            for (int fn = 0; fn < FN; ++fn)
                acc[0][fm][fn] = __builtin_amdgcn_mfma_f32_16x16x32_bf16(
                    afr0[fm], bfr[fn], acc[0][fm][fn], 0, 0, 0);
        #pragma unroll
        for (int fm = 0; fm < 4; ++fm)
            #pragma unroll
            for (int fn = 0; fn < FN; ++fn)
                acc[1][fm][fn] = __builtin_amdgcn_mfma_f32_16x16x32_bf16(
                    afr1[fm], bfr[fn], acc[1][fm][fn], 0, 0, 0);
        VMW2L();                                        // tile t+1 fully landed (2L outstanding)
        asm volatile("s_barrier" ::: "memory");         // ... before tile t+1's reads
    }
#undef STGA
#undef STGB
#undef VMW2L
    asm volatile("s_waitcnt vmcnt(0)" ::: "memory");

    if constexpr (OMODE == 0) {
        float* C = (float*)Cv;
        #pragma unroll
        for (int qm = 0; qm < 2; ++qm)
            #pragma unroll
            for (int fm = 0; fm < 4; ++fm)
                #pragma unroll
                for (int fn = 0; fn < FN; ++fn) {
                    const size_t col = col0 + wn*(FN*16) + fn*16 + lc;
                    #pragma unroll
                    for (int rr = 0; rr < 4; ++rr) {
                        const size_t row = row0 + wm*128 + qm*64 + fm*16 + lg*4 + rr;
                        C[row * N + col] = acc[qm][fm][fn][rr];
                    }
                }
    } else if constexpr (OMODE == 1) {
        __hip_bfloat16* C = (__hip_bfloat16*)Cv;
        #pragma unroll
        for (int qm = 0; qm < 2; ++qm)
            #pragma unroll
            for (int fm = 0; fm < 4; ++fm)
                #pragma unroll
                for (int fn = 0; fn < FN; ++fn) {
                    const size_t col = col0 + wn*(FN*16) + fn*16 + lc;
                    #pragma unroll
                    for (int rr = 0; rr < 4; ++rr) {
                        const size_t row = row0 + wm*128 + qm*64 + fm*16 + lg*4 + rr;
                        C[row * N + col] = __float2bfloat16(acc[qm][fm][fn][rr]);
                    }
                }
    } else {                                            // OMODE 2: KV split (FN==2, BN=128)
        if (bx < 8) {                                   // K columns -> kf bf16, LD 1024
            __hip_bfloat16* C = (__hip_bfloat16*)Cv;
            #pragma unroll
            for (int qm = 0; qm < 2; ++qm)
                #pragma unroll
                for (int fm = 0; fm < 4; ++fm)
                    #pragma unroll
                    for (int fn = 0; fn < FN; ++fn) {
                        const size_t col = col0 + wn*32 + fn*16 + lc;
                        #pragma unroll
                        for (int rr = 0; rr < 4; ++rr) {
                            const size_t row = row0 + wm*128 + qm*64 + fm*16 + lg*4 + rr;
                            C[row * 1024 + col] = __float2bfloat16(acc[qm][fm][fn][rr]);
                        }
                    }
        } else {                                        // V columns -> vt (B,KVH,D,S) via LDS
            __hip_bfloat16* lt = (__hip_bfloat16*)L;    // [128 d][264 pad]
            __syncthreads();
            #pragma unroll
            for (int qm = 0; qm < 2; ++qm)
                #pragma unroll
                for (int fm = 0; fm < 4; ++fm)
                    #pragma unroll
                    for (int fn = 0; fn < FN; ++fn) {
                        const int cl = wn*32 + fn*16 + lc;
                        #pragma unroll
                        for (int rr = 0; rr < 4; ++rr) {
                            const int rl = wm*128 + qm*64 + fm*16 + lg*4 + rr;
                            lt[cl*264 + rl] = __float2bfloat16(acc[qm][fm][fn][rr]);
                        }
                    }
            __syncthreads();
            const int bb = (int)(row0 >> 11), s0 = (int)(row0 & 2047);
            const int g  = (int)((col0 - 1024) >> 7);
            __hip_bfloat16* vto = (__hip_bfloat16*)C2 + (((size_t)bb*KVH_ + g) * D_) * (size_t)S_;
            const int d = tid >> 2, sc0 = (tid & 3) * 64;
            #pragma unroll
            for (int j = 0; j < 64; j += 8) {
                bf16x8 v = *(const bf16x8*)&lt[d*264 + sc0 + j];
                *(bf16x8*)&vto[(size_t)d*S_ + s0 + sc0 + j] = v;
            }
        }
    }
}

// ------------------------------------------------- per-head LN + interleaved RoPE (bf16 in)
// used only for K.  in: x (B*S, LD) bf16.  out: (B, NH, S, D) bf16.
template <int NH, int LD, int XOFF>
__global__ __launch_bounds__(256) void ln_rope(const __hip_bfloat16* __restrict__ x,
                                               const float* __restrict__ wln,
                                               const float* __restrict__ cosT,
                                               const float* __restrict__ sinT,
                                               const int* __restrict__ pids,
                                               __hip_bfloat16* __restrict__ out) {
    const int lane = threadIdx.x & 63, wv = threadIdx.x >> 6;
    const int r = blockIdx.x * 4 + wv;
    const int h = r % NH;
    const int bs = r / NH;
    const int b = bs / S_, s = bs % S_;
    const __hip_bfloat162 xv2 = *(const __hip_bfloat162*)(x + (size_t)bs * LD + XOFF + h*D_ + lane*2);
    const float x0 = __bfloat162float(xv2.x), x1 = __bfloat162float(xv2.y);
    float sum = x0 + x1;
    #pragma unroll
    for (int o = 32; o; o >>= 1) sum += __shfl_xor(sum, o);
    const float mu = sum * (1.f / D_);
    const float dx = x0 - mu, dy = x1 - mu;
    float vs = dx*dx + dy*dy;
    #pragma unroll
    for (int o = 32; o; o >>= 1) vs += __shfl_xor(vs, o);
    const float rs = rsqrtf(vs * (1.f / D_) + 1e-5f);
    const float2 w2 = *(const float2*)(wln + lane*2);
    const float y0 = w2.x * dx * rs, y1 = w2.y * dy * rs;
    const int p = pids[bs];
    const float2 c  = *(const float2*)(cosT + (size_t)p * D_ + lane*2);
    const float2 sn = *(const float2*)(sinT + (size_t)p * D_ + lane*2);
    __hip_bfloat162 ov;
    ov.x = __float2bfloat16(y0 * c.x - y1 * sn.x);
    ov.y = __float2bfloat16(y1 * c.y + y0 * sn.y);
    *(__hip_bfloat162*)(out + (((size_t)b * NH + h) * S_ + s) * D_ + lane*2) = ov;
}

// chunk swizzle for K tile (16B chunks, 16/row)
static __device__ __forceinline__ int sigk_(int r) { return (r & 3) | ((r >> 1) & 4); }

// ------------------------------------------------- sliding-window GQA flash attention v4
// (unchanged from R10 — 8 waves / 128 q-rows, fused Q LN+RoPE, counted vmcnt staging)
__global__ __launch_bounds__(512, 4) void attn_fwd(const __hip_bfloat16* __restrict__ qfb,
                                                   const __hip_bfloat16* __restrict__ kr,
                                                   const __hip_bfloat16* __restrict__ vt,
                                                   const float* __restrict__ qnw,
                                                   const float* __restrict__ cosT,
                                                   const float* __restrict__ sinT,
                                                   const int* __restrict__ pids,
                                                   __hip_bfloat16* __restrict__ ao) {
    __shared__ __align__(16) __hip_bfloat16 Ksl[2][64*D_];    // 2 x 16KB
    __shared__ __align__(16) __hip_bfloat16 Vsl[2][D_*64];    // 2 x 16KB
    const int tid = threadIdx.x;
    const int lane = tid & 63, w = tid >> 6;     // 8 waves
    const int lq = lane & 15, lg = lane >> 4;
    const int blk = blockIdx.x;
    const int qt = blk & 15;
    const int bh = blk >> 4;
    const int h = bh & (H_-1), b = bh >> 5;
    const int g = h >> 2;
    const int q0 = qt*128 + w*16;
    const int q  = q0 + lq;

    const __hip_bfloat16* kbase = kr + ((size_t)b*KVH_ + g) * (size_t)S_ * D_;
    const __hip_bfloat16* vbase = vt + ((size_t)b*KVH_ + g) * (size_t)D_ * S_;

    const int srK = lane >> 4, scK = lane & 15;
    const int srV = lane >> 3, scV = lane & 7;

#define STAGE(nb, k0s) do {                                                              \
    _Pragma("unroll")                                                                    \
    for (int s_ = 0; s_ < 2; ++s_) {                                                     \
        const int rK_ = w*8 + s_*4 + srK;                                                \
        const __hip_bfloat16* srcK_ = kbase + (size_t)((k0s) + rK_)*D_                   \
                                      + ((scK ^ sigk_(rK_)) * 8);                        \
        __builtin_amdgcn_global_load_lds((const GAS void*)srcK_,                         \
            (LAS void*)&Ksl[nb][(w*8 + s_*4)*D_], 16, 0, 0);                             \
    }                                                                                    \
    _Pragma("unroll")                                                                    \
    for (int s_ = 0; s_ < 2; ++s_) {                                                     \
        const int dV_ = w*16 + s_*8 + srV;                                               \
        const __hip_bfloat16* srcV_ = vbase + (size_t)dV_*S_ + (k0s)                     \
                                      + ((scV ^ (dV_ & 7)) * 8);                         \
        __builtin_amdgcn_global_load_lds((const GAS void*)srcV_,                         \
            (LAS void*)&Vsl[nb][(w*16 + s_*8)*64], 16, 0, 0);                            \
    }                                                                                    \
} while (0)

    int kst = qt*128 - (WIN_ - 1); if (kst < 0) kst = 0; kst &= ~63;
    const int nt = qt*2 + 2 - (kst >> 6);

    union { bf16x8 v; __hip_bfloat16 e[8]; } qraw[4];
    const __hip_bfloat16* qb2 = qfb + ((size_t)(b*S_ + q)) * HID_ + h*D_;
    #pragma unroll
    for (int kk = 0; kk < 4; ++kk)
        qraw[kk].v = *(const bf16x8*)(qb2 + kk*32 + lg*8);
    const int p = pids[b*S_ + q];

    STAGE(0, kst);

    float sum = 0.f;
    #pragma unroll
    for (int kk = 0; kk < 4; ++kk)
        #pragma unroll
        for (int j = 0; j < 8; ++j) sum += __bfloat162float(qraw[kk].e[j]);
    sum += __shfl_xor(sum, 16); sum += __shfl_xor(sum, 32);
    const float mu = sum * (1.f / D_);
    float vsq = 0.f;
    #pragma unroll
    for (int kk = 0; kk < 4; ++kk)
        #pragma unroll
        for (int j = 0; j < 8; ++j) {
            const float dxx = __bfloat162float(qraw[kk].e[j]) - mu;
            vsq += dxx * dxx;
        }
    vsq += __shfl_xor(vsq, 16); vsq += __shfl_xor(vsq, 32);
    const float rsq = rsqrtf(vsq * (1.f / D_) + 1e-5f);

    bf16x8 qf[4];
    #pragma unroll
    for (int kk = 0; kk < 4; ++kk) {
        const int d0 = kk*32 + lg*8;
        float wl[8], cc[8], ss[8], y[8];
        *(float4*)&wl[0] = *(const float4*)(qnw + d0);
        *(float4*)&wl[4] = *(const float4*)(qnw + d0 + 4);
        *(float4*)&cc[0] = *(const float4*)(cosT + (size_t)p*D_ + d0);
        *(float4*)&cc[4] = *(const float4*)(cosT + (size_t)p*D_ + d0 + 4);
        *(float4*)&ss[0] = *(const float4*)(sinT + (size_t)p*D_ + d0);
        *(float4*)&ss[4] = *(const float4*)(sinT + (size_t)p*D_ + d0 + 4);
        #pragma unroll
        for (int j = 0; j < 8; ++j)
            y[j] = wl[j] * (__bfloat162float(qraw[kk].e[j]) - mu) * rsq;
        union { bf16x8 v; __hip_bfloat16 e[8]; } qo;
        #pragma unroll
        for (int mpair = 0; mpair < 4; ++mpair) {
            qo.e[2*mpair]   = __float2bfloat16(y[2*mpair]   * cc[2*mpair]   - y[2*mpair+1] * ss[2*mpair]);
            qo.e[2*mpair+1] = __float2bfloat16(y[2*mpair+1] * cc[2*mpair+1] + y[2*mpair]   * ss[2*mpair+1]);
        }
        qf[kk] = qo.v;
    }

    f32x4 o[8] = {};
    float m = -1e30f, l = 0.f;
    const int kldrow = 8*(lq >> 2) + (lq & 3);

    for (int t = 0; t < nt; ++t) {
        const int k0 = kst + t*64;
        const int buf = t & 1;
        if (t + 1 < nt) {
            STAGE((t + 1) & 1, k0 + 64);
            asm volatile("s_waitcnt vmcnt(4)" ::: "memory");
        } else {
            asm volatile("s_waitcnt vmcnt(0)" ::: "memory");
        }
        __builtin_amdgcn_s_barrier();

        f32x4 sc[2][2] = {};
        __builtin_amdgcn_s_setprio(1);
        #pragma unroll
        for (int kb = 0; kb < 2; ++kb)
            #pragma unroll
            for (int f = 0; f < 2; ++f) {
                const int rA = kb*32 + 4*f + kldrow;
                const __hip_bfloat16* kp = &Ksl[buf][rA*D_];
                #pragma unroll
                for (int kk = 0; kk < 4; ++kk) {
                    bf16x8 ka = *(const bf16x8*)(kp + (((kk*4 + lg) ^ sigk_(rA)) * 8));
                    sc[kb][f] = __builtin_amdgcn_mfma_f32_16x16x32_bf16(ka, qf[kk], sc[kb][f], 0, 0, 0);
                }
            }
        __builtin_amdgcn_s_setprio(0);

        const int dqk = q - (k0 + 8*lg);
        float pv[16];
        float mx = -INFINITY;
        #pragma unroll
        for (int kb = 0; kb < 2; ++kb)
            #pragma unroll
            for (int f = 0; f < 2; ++f)
                #pragma unroll
                for (int r = 0; r < 4; ++r) {
                    const int c = kb*32 + 4*f + r;
                    const int d = dqk - c;
                    float v = (d >= 0 && d < WIN_) ? sc[kb][f][r] * SL2E_ : -INFINITY;
                    pv[kb*8 + f*4 + r] = v;
                    mx = fmaxf(mx, v);
                }
        mx = fmaxf(mx, __shfl_xor(mx, 16));
        mx = fmaxf(mx, __shfl_xor(mx, 32));
        const float mn = fmaxf(m, mx);
        const float alpha = exp2f(m - mn);
        float ls = 0.f;
        union { bf16x8 v; __hip_bfloat16 e[8]; } pu[2];
        #pragma unroll
        for (int kb = 0; kb < 2; ++kb)
            #pragma unroll
            for (int j = 0; j < 8; ++j) {
                const float pw = exp2f(pv[kb*8 + j] - mn);
                ls += pw;
                pu[kb].e[j] = __float2bfloat16(pw);
            }
        ls += __shfl_xor(ls, 16);
        ls += __shfl_xor(ls, 32);
        l = l * alpha + ls;
        m = mn;
        #pragma unroll
        for (int n = 0; n < 8; ++n) {
            o[n][0] *= alpha; o[n][1] *= alpha; o[n][2] *= alpha; o[n][3] *= alpha;
        }

        __builtin_amdgcn_s_setprio(1);
        #pragma unroll
        for (int kb = 0; kb < 2; ++kb)
            #pragma unroll
            for (int n = 0; n < 8; ++n) {
                const int dR = n*16 + lq;
                bf16x8 vf8 = *(const bf16x8*)(&Vsl[buf][dR*64] + (((kb*4 + lg) ^ (dR & 7)) * 8));
                o[n] = __builtin_amdgcn_mfma_f32_16x16x32_bf16(vf8, pu[kb].v, o[n], 0, 0, 0);
            }
        __builtin_amdgcn_s_setprio(0);

        if (t + 1 < nt) __builtin_amdgcn_s_barrier();
    }
#undef STAGE

    const float rinv = 1.f / l;
    #pragma unroll
    for (int n = 0; n < 8; ++n) {
        union { bf16x4 v; __hip_bfloat16 e[4]; } ov;
        #pragma unroll
        for (int r = 0; r < 4; ++r) ov.e[r] = __float2bfloat16(o[n][r] * rinv);
        *(bf16x4*)(ao + ((size_t)b*S_ + q)*(H_*D_) + h*D_ + n*16 + lg*4) = ov.v;
    }
}

// ----------------------------------------------------------------- host
extern "C" void kernel_launch(void* const* d_in, const int* in_sizes, int n_in,
                              void* d_out, int out_size, void* d_ws, size_t ws_size,
                              hipStream_t stream) {
    const float* hidden = (const float*)d_in[0];
    const int*   pids   = (const int*)  d_in[1];
    const float* cosT   = (const float*)d_in[2];
    const float* sinT   = (const float*)d_in[3];
    const float* wq     = (const float*)d_in[4];
    const float* wk     = (const float*)d_in[5];
    const float* wv     = (const float*)d_in[6];
    const float* wo     = (const float*)d_in[7];
    const float* qnw    = (const float*)d_in[8];
    const float* knw    = (const float*)d_in[9];
    float* out = (float*)d_out;

    char* base = (char*)d_ws;
    size_t off = 0;
    auto take = [&](size_t bytes) -> void* {
        void* q = base + off;
        off = (off + bytes + 255) & ~(size_t)255;
        return q;
    };
    __hip_bfloat16* qfb  = (__hip_bfloat16*)take((size_t)NROW_*HID_*2);   // Q proj bf16
    __hip_bfloat16* ao   = (__hip_bfloat16*)take((size_t)NROW_*HID_*2);   // attn out bf16
    __hip_bfloat16* kf   = (__hip_bfloat16*)take((size_t)NROW_*1024*2);   // K proj bf16
    __hip_bfloat16* hb   = (__hip_bfloat16*)take((size_t)NROW_*HID_*2);
    __hip_bfloat16* wqT  = (__hip_bfloat16*)take((size_t)HID_*HID_*2);
    __hip_bfloat16* wkvT = (__hip_bfloat16*)take((size_t)NKV_*HID_*2);
    __hip_bfloat16* woT  = (__hip_bfloat16*)take((size_t)HID_*HID_*2);
    __hip_bfloat16* kr   = (__hip_bfloat16*)take((size_t)B_*KVH_*S_*D_*2);
    __hip_bfloat16* vt   = (__hip_bfloat16*)take((size_t)B_*KVH_*S_*D_*2);

    if (off > ws_size) {
        fprintf(stderr, "WORKSPACE TOO SMALL: need %zu have %zu\n", off, ws_size);
        return;
    }

    // 1. merged prep: hidden convert + 4 weight transposes (1 launch)
    prep_all<<<16384 + 40960, 256, 0, stream>>>(hidden, wq, wk, wv, wo, hb, wqT, wkvT, woT);

    // 2. projections — every grid exactly 256 blocks (1 round on 256 CUs)
    gemm_t<4,1><<<(NROW_/256)*(HID_/256), 512, 0, stream>>>(hb, wqT,  qfb, nullptr, NROW_, HID_, HID_, HID_/256);
    gemm_t<2,2><<<(NROW_/256)*(NKV_/128), 512, 0, stream>>>(hb, wkvT, kf,  vt,      NROW_, NKV_, HID_, NKV_/128);

    // 3. LN + RoPE for K only (Q is fused into attention)
    ln_rope<KVH_, 1024, 0><<<(B_*S_*KVH_)/4, 256, 0, stream>>>(kf, knw, cosT, sinT, pids, kr);

    // 4. attention (8 waves, 128 q-rows/block, fused Q LN+RoPE)
    attn_fwd<<<B_*H_*(S_/128), 512, 0, stream>>>(qfb, kr, vt, qnw, cosT, sinT, pids, ao);

    // 5. output projection -> d_out (f32)
    gemm_t<4,0><<<(NROW_/256)*(HID_/256), 512, 0, stream>>>(ao, woT, out, nullptr, NROW_, HID_, H_*D_, HID_/256);
}

// Round 12
// 465.000 us; speedup vs baseline: 1.0001x; 1.0001x over previous
//
#include <hip/hip_runtime.h>
#include <hip/hip_bf16.h>
#include <cstdio>
#include <cstdint>

#define B_    2
#define S_    2048
#define H_    32
#define KVH_  8
#define D_    128
#define HID_  4096
#define WIN_  512
#define NROW_ (B_*S_)          // 4096 rows for projection GEMMs
#define NKV_  2048             // fused k|v output width
#define SCALE_ 0.08838834764831845f          // 128^-0.5
#define SL2E_  0.12751744932973953f          // SCALE_ * log2(e)

typedef __attribute__((ext_vector_type(8))) __bf16 bf16x8;
typedef __attribute__((ext_vector_type(4))) __bf16 bf16x4;
typedef __attribute__((ext_vector_type(4))) float  f32x4;

#define GAS __attribute__((address_space(1)))
#define LAS __attribute__((address_space(3)))

// ------------------------------------------------- merged prep: cvt hidden + 4 weight transposes
__global__ __launch_bounds__(256) void prep_all(const float* __restrict__ hidden,
                                                const float* __restrict__ wq,
                                                const float* __restrict__ wk,
                                                const float* __restrict__ wv,
                                                const float* __restrict__ wo,
                                                __hip_bfloat16* __restrict__ hb,
                                                __hip_bfloat16* __restrict__ wqT,
                                                __hip_bfloat16* __restrict__ wkvT,
                                                __hip_bfloat16* __restrict__ woT) {
    __shared__ float t[32][33];
    const int bid = blockIdx.x;
    if (bid < 16384) {
        const int i = (bid * 256 + threadIdx.x) * 4;
        float4 v = *(const float4*)(hidden + i);
        __hip_bfloat162 a, b;
        a.x = __float2bfloat16(v.x); a.y = __float2bfloat16(v.y);
        b.x = __float2bfloat16(v.z); b.y = __float2bfloat16(v.w);
        *(__hip_bfloat162*)(hb + i)     = a;
        *(__hip_bfloat162*)(hb + i + 2) = b;
        return;
    }
    const int tx = threadIdx.x & 31, ty = threadIdx.x >> 5;
    const int id = bid - 16384;
    const float* src; __hip_bfloat16* dst; int C, idx;   // R always 4096
    if (id < 16384)      { src = wq; dst = wqT;  C = 4096; idx = id; }
    else if (id < 20480) { src = wk; dst = wkvT; C = 1024; idx = id - 16384; }
    else if (id < 24576) { src = wv; dst = wkvT + (size_t)1024*HID_; C = 1024; idx = id - 20480; }
    else                 { src = wo; dst = woT;  C = 4096; idx = id - 24576; }
    const int ctiles = C >> 5;
    const int c0 = (idx % ctiles) * 32, r0 = (idx / ctiles) * 32;
    #pragma unroll
    for (int i = 0; i < 4; ++i)
        t[ty + 8*i][tx] = src[(size_t)(r0 + ty + 8*i) * C + c0 + tx];
    __syncthreads();
    #pragma unroll
    for (int i = 0; i < 4; ++i)
        dst[(size_t)(c0 + ty + 8*i) * HID_ + r0 + tx] = __float2bfloat16(t[tx][ty + 8*i]);
}

// ------------------------------------------------- GEMM 256xBN, BK=32, ring-4, 1-barrier/tile
// R12: register one-tile lookahead.  Per tile t, this tile's 16*FN q0-MFMAs consume B+Aq0
// fragments PREFETCHED during tile t-1 (their lgkm drained long ago -> free), while this
// tile's ds_reads (Aq1 of slot t, then B+Aq0 of slot t+1) stream through the LDS pipe
// UNDER the MFMAs.  Aq1-dependent q1-MFMAs gate on counted lgkmcnt(4+FN) (+sched_barrier,
// rule 18).  Confirm depth deepened: trailing vmcnt(L) (L = loads/thread/tile) confirms
// slot t+2 by end of tile t, making the slot-(t+1) prefetch reads in tile t+1 race-free.
// WAR: slot (t+1)&3 next written by STG(t+5) in tile t+2 — two barriers after the
// prefetch reads complete.  nt even for all uses; frag sets alternated by unroll-2 (rule 20).
template <int FN, int OMODE>
__global__ __launch_bounds__(512, 2) void gemm_t(const __hip_bfloat16* __restrict__ A,
                                                 const __hip_bfloat16* __restrict__ Bt,
                                                 void* __restrict__ Cv, void* __restrict__ C2,
                                                 int M, int N, int K, int nbx) {
    constexpr int BN   = FN * 64;
    constexpr int BLD  = BN / 128;                      // B stage loads/thread/tile (2 or 1)
    constexpr int LPT  = 2 + BLD;                       // stage loads/thread/tile
    constexpr int SLOT = (256 + BN) * 32;               // elems per ring slot (A then B)
    __shared__ __align__(16) __hip_bfloat16 L[4 * SLOT];
    const int tid  = threadIdx.x;
    const int lane = tid & 63, w = tid >> 6;
    const int wm = w >> 2, wn = w & 3;                  // 2 x 4 wave grid
    const int lc = lane & 15, lg = lane >> 4;
    const int nwg = gridDim.x, cpx = nwg >> 3;
    const int bid = blockIdx.x;
    const int swz = (bid & 7) * cpx + (bid >> 3);
    const int by = swz / nbx, bx = swz - by * nbx;
    const size_t row0 = (size_t)by * 256, col0 = (size_t)bx * BN;
    const int nt = K >> 5;                              // BK = 32, nt even

    const int srow = tid >> 2;
    const int spc  = tid & 3;
    const int slx  = spc ^ ((srow >> 1) & 3);
    const __hip_bfloat16* Ab = A  + row0 * K;
    const __hip_bfloat16* Bb = Bt + col0 * K;

#define STGA(tile_) do {                                                                   \
    const int ss_ = (tile_) & 3;                                                           \
    const int kt_ = ((tile_) < nt) ? (tile_) : (nt - 1);                                   \
    _Pragma("unroll")                                                                      \
    for (int rh_ = 0; rh_ < 2; ++rh_)                                                      \
        __builtin_amdgcn_global_load_lds(                                                  \
            (const GAS void*)(Ab + (size_t)(rh_*128 + srow) * K + kt_*32 + slx*8),         \
            (LAS void*)&L[ss_*SLOT + rh_*4096 + w*512], 16, 0, 0);                         \
} while (0)

#define STGB(tile_) do {                                                                   \
    const int ss_ = (tile_) & 3;                                                           \
    const int kt_ = ((tile_) < nt) ? (tile_) : (nt - 1);                                   \
    _Pragma("unroll")                                                                      \
    for (int bh_ = 0; bh_ < BLD; ++bh_)                                                    \
        __builtin_amdgcn_global_load_lds(                                                  \
            (const GAS void*)(Bb + (size_t)(bh_*128 + srow) * K + kt_*32 + slx*8),         \
            (LAS void*)&L[ss_*SLOT + 8192 + bh_*4096 + w*512], 16, 0, 0);                  \
} while (0)

#define VMWL() do {                                                                       \
    if constexpr (FN == 4) asm volatile("s_waitcnt vmcnt(4)" ::: "memory");               \
    else                   asm volatile("s_waitcnt vmcnt(3)" ::: "memory");               \
} while (0)

#define RDB(dst_, slot_) do {                                                             \
    _Pragma("unroll")                                                                     \
    for (int fn = 0; fn < FN; ++fn) {                                                     \
        const int rB = wn*(FN*16) + fn*16 + lc;                                           \
        dst_[fn] = *(const bf16x8*)&L[(slot_)*SLOT + 8192 + rB*32 + ((lg ^ ((rB >> 1) & 3)) * 8)]; \
    }                                                                                     \
} while (0)

#define RDA0(dst_, slot_) do {                                                            \
    _Pragma("unroll")                                                                     \
    for (int fm = 0; fm < 4; ++fm) {                                                      \
        const int rA = wm*128 + fm*16 + lc;                                               \
        dst_[fm] = *(const bf16x8*)&L[(slot_)*SLOT + rA*32 + ((lg ^ ((rA >> 1) & 3)) * 8)]; \
    }                                                                                     \
} while (0)

    f32x4 acc[2][4][FN] = {};
    bf16x8 bfrA[FN], bfrB[FN], a0A[4], a0B[4], afr1[4];

    // prologue: stage tiles 0..2; vmcnt(L) confirms slots 0 AND 1; prefetch slot 0 frags
    STGA(0); STGB(0); STGA(1); STGB(1); STGA(2); STGB(2);
    VMWL();
    asm volatile("s_barrier" ::: "memory");
    RDB(bfrA, 0); RDA0(a0A, 0);

#define TILE(tt_, BC, A0C, BNx, A0N) do {                                                 \
    const int sc_ = (tt_) & 3;                                                            \
    const int sn_ = (((tt_) + 1 < nt) ? ((tt_) + 1) : (nt - 1)) & 3;                      \
    /* in-tile A-q1 reads of slot t (oldest lgkm group) */                                \
    _Pragma("unroll")                                                                     \
    for (int fm = 0; fm < 4; ++fm) {                                                      \
        const int rA = wm*128 + 64 + fm*16 + lc;                                          \
        afr1[fm] = *(const bf16x8*)&L[sc_*SLOT + rA*32 + ((lg ^ ((rA >> 1) & 3)) * 8)];   \
    }                                                                                     \
    __builtin_amdgcn_sched_barrier(0);   /* pin: afr1 group older than prefetch group */  \
    RDB(BNx, sn_); RDA0(A0N, sn_);       /* prefetch slot t+1 -> next-tile regs */        \
    STGA((tt_) + 3);  STGB((tt_) + 3);                                                    \
    /* q0 MFMAs: consume LAST tile's prefetched regs (lgkm already drained) */            \
    _Pragma("unroll")                                                                     \
    for (int fm = 0; fm < 4; ++fm)                                                        \
        _Pragma("unroll")                                                                 \
        for (int fn = 0; fn < FN; ++fn)                                                   \
            acc[0][fm][fn] = __builtin_amdgcn_mfma_f32_16x16x32_bf16(                     \
                A0C[fm], BC[fn], acc[0][fm][fn], 0, 0, 0);                                \
    if constexpr (FN == 4) asm volatile("s_waitcnt lgkmcnt(8)" ::: "memory");             \
    else                   asm volatile("s_waitcnt lgkmcnt(6)" ::: "memory");             \
    __builtin_amdgcn_sched_barrier(0);   /* rule 18: MFMA must not hoist past the wait */ \
    _Pragma("unroll")                                                                     \
    for (int fm = 0; fm < 4; ++fm)                                                        \
        _Pragma("unroll")                                                                 \
        for (int fn = 0; fn < FN; ++fn)                                                   \
            acc[1][fm][fn] = __builtin_amdgcn_mfma_f32_16x16x32_bf16(                     \
                afr1[fm], BC[fn], acc[1][fm][fn], 0, 0, 0);                               \
    VMWL();                              /* confirms slot t+2 for next tile's prefetch */ \
    asm volatile("s_barrier" ::: "memory");                                               \
} while (0)

    for (int t = 0; t < nt; t += 2) {
        TILE(t,     bfrA, a0A, bfrB, a0B);
        TILE(t + 1, bfrB, a0B, bfrA, a0A);
    }
#undef TILE
#undef RDB
#undef RDA0
#undef STGA
#undef STGB
#undef VMWL
    asm volatile("s_waitcnt vmcnt(0)" ::: "memory");

    if constexpr (OMODE == 0) {
        float* C = (float*)Cv;
        #pragma unroll
        for (int qm = 0; qm < 2; ++qm)
            #pragma unroll
            for (int fm = 0; fm < 4; ++fm)
                #pragma unroll
                for (int fn = 0; fn < FN; ++fn) {
                    const size_t col = col0 + wn*(FN*16) + fn*16 + lc;
                    #pragma unroll
                    for (int rr = 0; rr < 4; ++rr) {
                        const size_t row = row0 + wm*128 + qm*64 + fm*16 + lg*4 + rr;
                        C[row * N + col] = acc[qm][fm][fn][rr];
                    }
                }
    } else if constexpr (OMODE == 1) {
        __hip_bfloat16* C = (__hip_bfloat16*)Cv;
        #pragma unroll
        for (int qm = 0; qm < 2; ++qm)
            #pragma unroll
            for (int fm = 0; fm < 4; ++fm)
                #pragma unroll
                for (int fn = 0; fn < FN; ++fn) {
                    const size_t col = col0 + wn*(FN*16) + fn*16 + lc;
                    #pragma unroll
                    for (int rr = 0; rr < 4; ++rr) {
                        const size_t row = row0 + wm*128 + qm*64 + fm*16 + lg*4 + rr;
                        C[row * N + col] = __float2bfloat16(acc[qm][fm][fn][rr]);
                    }
                }
    } else {                                            // OMODE 2: KV split (FN==2, BN=128)
        if (bx < 8) {                                   // K columns -> kf bf16, LD 1024
            __hip_bfloat16* C = (__hip_bfloat16*)Cv;
            #pragma unroll
            for (int qm = 0; qm < 2; ++qm)
                #pragma unroll
                for (int fm = 0; fm < 4; ++fm)
                    #pragma unroll
                    for (int fn = 0; fn < FN; ++fn) {
                        const size_t col = col0 + wn*32 + fn*16 + lc;
                        #pragma unroll
                        for (int rr = 0; rr < 4; ++rr) {
                            const size_t row = row0 + wm*128 + qm*64 + fm*16 + lg*4 + rr;
                            C[row * 1024 + col] = __float2bfloat16(acc[qm][fm][fn][rr]);
                        }
                    }
        } else {                                        // V columns -> vt (B,KVH,D,S) via LDS
            __hip_bfloat16* lt = (__hip_bfloat16*)L;    // [128 d][264 pad]
            __syncthreads();
            #pragma unroll
            for (int qm = 0; qm < 2; ++qm)
                #pragma unroll
                for (int fm = 0; fm < 4; ++fm)
                    #pragma unroll
                    for (int fn = 0; fn < FN; ++fn) {
                        const int cl = wn*32 + fn*16 + lc;
                        #pragma unroll
                        for (int rr = 0; rr < 4; ++rr) {
                            const int rl = wm*128 + qm*64 + fm*16 + lg*4 + rr;
                            lt[cl*264 + rl] = __float2bfloat16(acc[qm][fm][fn][rr]);
                        }
                    }
            __syncthreads();
            const int bb = (int)(row0 >> 11), s0 = (int)(row0 & 2047);
            const int g  = (int)((col0 - 1024) >> 7);
            __hip_bfloat16* vto = (__hip_bfloat16*)C2 + (((size_t)bb*KVH_ + g) * D_) * (size_t)S_;
            const int d = tid >> 2, sc0 = (tid & 3) * 64;
            #pragma unroll
            for (int j = 0; j < 64; j += 8) {
                bf16x8 v = *(const bf16x8*)&lt[d*264 + sc0 + j];
                *(bf16x8*)&vto[(size_t)d*S_ + s0 + sc0 + j] = v;
            }
        }
    }
}

// ------------------------------------------------- per-head LN + interleaved RoPE (bf16 in)
// used only for K.  in: x (B*S, LD) bf16.  out: (B, NH, S, D) bf16.
template <int NH, int LD, int XOFF>
__global__ __launch_bounds__(256) void ln_rope(const __hip_bfloat16* __restrict__ x,
                                               const float* __restrict__ wln,
                                               const float* __restrict__ cosT,
                                               const float* __restrict__ sinT,
                                               const int* __restrict__ pids,
                                               __hip_bfloat16* __restrict__ out) {
    const int lane = threadIdx.x & 63, wv = threadIdx.x >> 6;
    const int r = blockIdx.x * 4 + wv;
    const int h = r % NH;
    const int bs = r / NH;
    const int b = bs / S_, s = bs % S_;
    const __hip_bfloat162 xv2 = *(const __hip_bfloat162*)(x + (size_t)bs * LD + XOFF + h*D_ + lane*2);
    const float x0 = __bfloat162float(xv2.x), x1 = __bfloat162float(xv2.y);
    float sum = x0 + x1;
    #pragma unroll
    for (int o = 32; o; o >>= 1) sum += __shfl_xor(sum, o);
    const float mu = sum * (1.f / D_);
    const float dx = x0 - mu, dy = x1 - mu;
    float vs = dx*dx + dy*dy;
    #pragma unroll
    for (int o = 32; o; o >>= 1) vs += __shfl_xor(vs, o);
    const float rs = rsqrtf(vs * (1.f / D_) + 1e-5f);
    const float2 w2 = *(const float2*)(wln + lane*2);
    const float y0 = w2.x * dx * rs, y1 = w2.y * dy * rs;
    const int p = pids[bs];
    const float2 c  = *(const float2*)(cosT + (size_t)p * D_ + lane*2);
    const float2 sn = *(const float2*)(sinT + (size_t)p * D_ + lane*2);
    __hip_bfloat162 ov;
    ov.x = __float2bfloat16(y0 * c.x - y1 * sn.x);
    ov.y = __float2bfloat16(y1 * c.y + y0 * sn.y);
    *(__hip_bfloat162*)(out + (((size_t)b * NH + h) * S_ + s) * D_ + lane*2) = ov;
}

// chunk swizzle for K tile (16B chunks, 16/row)
static __device__ __forceinline__ int sigk_(int r) { return (r & 3) | ((r >> 1) & 4); }

// ------------------------------------------------- sliding-window GQA flash attention v4
// (unchanged from R10 — 8 waves / 128 q-rows, fused Q LN+RoPE, counted vmcnt staging)
__global__ __launch_bounds__(512, 4) void attn_fwd(const __hip_bfloat16* __restrict__ qfb,
                                                   const __hip_bfloat16* __restrict__ kr,
                                                   const __hip_bfloat16* __restrict__ vt,
                                                   const float* __restrict__ qnw,
                                                   const float* __restrict__ cosT,
                                                   const float* __restrict__ sinT,
                                                   const int* __restrict__ pids,
                                                   __hip_bfloat16* __restrict__ ao) {
    __shared__ __align__(16) __hip_bfloat16 Ksl[2][64*D_];    // 2 x 16KB
    __shared__ __align__(16) __hip_bfloat16 Vsl[2][D_*64];    // 2 x 16KB
    const int tid = threadIdx.x;
    const int lane = tid & 63, w = tid >> 6;     // 8 waves
    const int lq = lane & 15, lg = lane >> 4;
    const int blk = blockIdx.x;
    const int qt = blk & 15;
    const int bh = blk >> 4;
    const int h = bh & (H_-1), b = bh >> 5;
    const int g = h >> 2;
    const int q0 = qt*128 + w*16;
    const int q  = q0 + lq;

    const __hip_bfloat16* kbase = kr + ((size_t)b*KVH_ + g) * (size_t)S_ * D_;
    const __hip_bfloat16* vbase = vt + ((size_t)b*KVH_ + g) * (size_t)D_ * S_;

    const int srK = lane >> 4, scK = lane & 15;
    const int srV = lane >> 3, scV = lane & 7;

#define STAGE(nb, k0s) do {                                                              \
    _Pragma("unroll")                                                                    \
    for (int s_ = 0; s_ < 2; ++s_) {                                                     \
        const int rK_ = w*8 + s_*4 + srK;                                                \
        const __hip_bfloat16* srcK_ = kbase + (size_t)((k0s) + rK_)*D_                   \
                                      + ((scK ^ sigk_(rK_)) * 8);                        \
        __builtin_amdgcn_global_load_lds((const GAS void*)srcK_,                         \
            (LAS void*)&Ksl[nb][(w*8 + s_*4)*D_], 16, 0, 0);                             \
    }                                                                                    \
    _Pragma("unroll")                                                                    \
    for (int s_ = 0; s_ < 2; ++s_) {                                                     \
        const int dV_ = w*16 + s_*8 + srV;                                               \
        const __hip_bfloat16* srcV_ = vbase + (size_t)dV_*S_ + (k0s)                     \
                                      + ((scV ^ (dV_ & 7)) * 8);                         \
        __builtin_amdgcn_global_load_lds((const GAS void*)srcV_,                         \
            (LAS void*)&Vsl[nb][(w*16 + s_*8)*64], 16, 0, 0);                            \
    }                                                                                    \
} while (0)

    int kst = qt*128 - (WIN_ - 1); if (kst < 0) kst = 0; kst &= ~63;
    const int nt = qt*2 + 2 - (kst >> 6);

    union { bf16x8 v; __hip_bfloat16 e[8]; } qraw[4];
    const __hip_bfloat16* qb2 = qfb + ((size_t)(b*S_ + q)) * HID_ + h*D_;
    #pragma unroll
    for (int kk = 0; kk < 4; ++kk)
        qraw[kk].v = *(const bf16x8*)(qb2 + kk*32 + lg*8);
    const int p = pids[b*S_ + q];

    STAGE(0, kst);

    float sum = 0.f;
    #pragma unroll
    for (int kk = 0; kk < 4; ++kk)
        #pragma unroll
        for (int j = 0; j < 8; ++j) sum += __bfloat162float(qraw[kk].e[j]);
    sum += __shfl_xor(sum, 16); sum += __shfl_xor(sum, 32);
    const float mu = sum * (1.f / D_);
    float vsq = 0.f;
    #pragma unroll
    for (int kk = 0; kk < 4; ++kk)
        #pragma unroll
        for (int j = 0; j < 8; ++j) {
            const float dxx = __bfloat162float(qraw[kk].e[j]) - mu;
            vsq += dxx * dxx;
        }
    vsq += __shfl_xor(vsq, 16); vsq += __shfl_xor(vsq, 32);
    const float rsq = rsqrtf(vsq * (1.f / D_) + 1e-5f);

    bf16x8 qf[4];
    #pragma unroll
    for (int kk = 0; kk < 4; ++kk) {
        const int d0 = kk*32 + lg*8;
        float wl[8], cc[8], ss[8], y[8];
        *(float4*)&wl[0] = *(const float4*)(qnw + d0);
        *(float4*)&wl[4] = *(const float4*)(qnw + d0 + 4);
        *(float4*)&cc[0] = *(const float4*)(cosT + (size_t)p*D_ + d0);
        *(float4*)&cc[4] = *(const float4*)(cosT + (size_t)p*D_ + d0 + 4);
        *(float4*)&ss[0] = *(const float4*)(sinT + (size_t)p*D_ + d0);
        *(float4*)&ss[4] = *(const float4*)(sinT + (size_t)p*D_ + d0 + 4);
        #pragma unroll
        for (int j = 0; j < 8; ++j)
            y[j] = wl[j] * (__bfloat162float(qraw[kk].e[j]) - mu) * rsq;
        union { bf16x8 v; __hip_bfloat16 e[8]; } qo;
        #pragma unroll
        for (int mpair = 0; mpair < 4; ++mpair) {
            qo.e[2*mpair]   = __float2bfloat16(y[2*mpair]   * cc[2*mpair]   - y[2*mpair+1] * ss[2*mpair]);
            qo.e[2*mpair+1] = __float2bfloat16(y[2*mpair+1] * cc[2*mpair+1] + y[2*mpair]   * ss[2*mpair+1]);
        }
        qf[kk] = qo.v;
    }

    f32x4 o[8] = {};
    float m = -1e30f, l = 0.f;
    const int kldrow = 8*(lq >> 2) + (lq & 3);

    for (int t = 0; t < nt; ++t) {
        const int k0 = kst + t*64;
        const int buf = t & 1;
        if (t + 1 < nt) {
            STAGE((t + 1) & 1, k0 + 64);
            asm volatile("s_waitcnt vmcnt(4)" ::: "memory");
        } else {
            asm volatile("s_waitcnt vmcnt(0)" ::: "memory");
        }
        __builtin_amdgcn_s_barrier();

        f32x4 sc[2][2] = {};
        __builtin_amdgcn_s_setprio(1);
        #pragma unroll
        for (int kb = 0; kb < 2; ++kb)
            #pragma unroll
            for (int f = 0; f < 2; ++f) {
                const int rA = kb*32 + 4*f + kldrow;
                const __hip_bfloat16* kp = &Ksl[buf][rA*D_];
                #pragma unroll
                for (int kk = 0; kk < 4; ++kk) {
                    bf16x8 ka = *(const bf16x8*)(kp + (((kk*4 + lg) ^ sigk_(rA)) * 8));
                    sc[kb][f] = __builtin_amdgcn_mfma_f32_16x16x32_bf16(ka, qf[kk], sc[kb][f], 0, 0, 0);
                }
            }
        __builtin_amdgcn_s_setprio(0);

        const int dqk = q - (k0 + 8*lg);
        float pv[16];
        float mx = -INFINITY;
        #pragma unroll
        for (int kb = 0; kb < 2; ++kb)
            #pragma unroll
            for (int f = 0; f < 2; ++f)
                #pragma unroll
                for (int r = 0; r < 4; ++r) {
                    const int c = kb*32 + 4*f + r;
                    const int d = dqk - c;
                    float v = (d >= 0 && d < WIN_) ? sc[kb][f][r] * SL2E_ : -INFINITY;
                    pv[kb*8 + f*4 + r] = v;
                    mx = fmaxf(mx, v);
                }
        mx = fmaxf(mx, __shfl_xor(mx, 16));
        mx = fmaxf(mx, __shfl_xor(mx, 32));
        const float mn = fmaxf(m, mx);
        const float alpha = exp2f(m - mn);
        float ls = 0.f;
        union { bf16x8 v; __hip_bfloat16 e[8]; } pu[2];
        #pragma unroll
        for (int kb = 0; kb < 2; ++kb)
            #pragma unroll
            for (int j = 0; j < 8; ++j) {
                const float pw = exp2f(pv[kb*8 + j] - mn);
                ls += pw;
                pu[kb].e[j] = __float2bfloat16(pw);
            }
        ls += __shfl_xor(ls, 16);
        ls += __shfl_xor(ls, 32);
        l = l * alpha + ls;
        m = mn;
        #pragma unroll
        for (int n = 0; n < 8; ++n) {
            o[n][0] *= alpha; o[n][1] *= alpha; o[n][2] *= alpha; o[n][3] *= alpha;
        }

        __builtin_amdgcn_s_setprio(1);
        #pragma unroll
        for (int kb = 0; kb < 2; ++kb)
            #pragma unroll
            for (int n = 0; n < 8; ++n) {
                const int dR = n*16 + lq;
                bf16x8 vf8 = *(const bf16x8*)(&Vsl[buf][dR*64] + (((kb*4 + lg) ^ (dR & 7)) * 8));
                o[n] = __builtin_amdgcn_mfma_f32_16x16x32_bf16(vf8, pu[kb].v, o[n], 0, 0, 0);
            }
        __builtin_amdgcn_s_setprio(0);

        if (t + 1 < nt) __builtin_amdgcn_s_barrier();
    }
#undef STAGE

    const float rinv = 1.f / l;
    #pragma unroll
    for (int n = 0; n < 8; ++n) {
        union { bf16x4 v; __hip_bfloat16 e[4]; } ov;
        #pragma unroll
        for (int r = 0; r < 4; ++r) ov.e[r] = __float2bfloat16(o[n][r] * rinv);
        *(bf16x4*)(ao + ((size_t)b*S_ + q)*(H_*D_) + h*D_ + n*16 + lg*4) = ov.v;
    }
}

// ----------------------------------------------------------------- host
extern "C" void kernel_launch(void* const* d_in, const int* in_sizes, int n_in,
                              void* d_out, int out_size, void* d_ws, size_t ws_size,
                              hipStream_t stream) {
    const float* hidden = (const float*)d_in[0];
    const int*   pids   = (const int*)  d_in[1];
    const float* cosT   = (const float*)d_in[2];
    const float* sinT   = (const float*)d_in[3];
    const float* wq     = (const float*)d_in[4];
    const float* wk     = (const float*)d_in[5];
    const float* wv     = (const float*)d_in[6];
    const float* wo     = (const float*)d_in[7];
    const float* qnw    = (const float*)d_in[8];
    const float* knw    = (const float*)d_in[9];
    float* out = (float*)d_out;

    char* base = (char*)d_ws;
    size_t off = 0;
    auto take = [&](size_t bytes) -> void* {
        void* q = base + off;
        off = (off + bytes + 255) & ~(size_t)255;
        return q;
    };
    __hip_bfloat16* qfb  = (__hip_bfloat16*)take((size_t)NROW_*HID_*2);   // Q proj bf16
    __hip_bfloat16* ao   = (__hip_bfloat16*)take((size_t)NROW_*HID_*2);   // attn out bf16
    __hip_bfloat16* kf   = (__hip_bfloat16*)take((size_t)NROW_*1024*2);   // K proj bf16
    __hip_bfloat16* hb   = (__hip_bfloat16*)take((size_t)NROW_*HID_*2);
    __hip_bfloat16* wqT  = (__hip_bfloat16*)take((size_t)HID_*HID_*2);
    __hip_bfloat16* wkvT = (__hip_bfloat16*)take((size_t)NKV_*HID_*2);
    __hip_bfloat16* woT  = (__hip_bfloat16*)take((size_t)HID_*HID_*2);
    __hip_bfloat16* kr   = (__hip_bfloat16*)take((size_t)B_*KVH_*S_*D_*2);
    __hip_bfloat16* vt   = (__hip_bfloat16*)take((size_t)B_*KVH_*S_*D_*2);

    if (off > ws_size) {
        fprintf(stderr, "WORKSPACE TOO SMALL: need %zu have %zu\n", off, ws_size);
        return;
    }

    // 1. merged prep: hidden convert + 4 weight transposes (1 launch)
    prep_all<<<16384 + 40960, 256, 0, stream>>>(hidden, wq, wk, wv, wo, hb, wqT, wkvT, woT);

    // 2. projections — every grid exactly 256 blocks (1 round on 256 CUs)
    gemm_t<4,1><<<(NROW_/256)*(HID_/256), 512, 0, stream>>>(hb, wqT,  qfb, nullptr, NROW_, HID_, HID_, HID_/256);
    gemm_t<2,2><<<(NROW_/256)*(NKV_/128), 512, 0, stream>>>(hb, wkvT, kf,  vt,      NROW_, NKV_, HID_, NKV_/128);

    // 3. LN + RoPE for K only (Q is fused into attention)
    ln_rope<KVH_, 1024, 0><<<(B_*S_*KVH_)/4, 256, 0, stream>>>(kf, knw, cosT, sinT, pids, kr);

    // 4. attention (8 waves, 128 q-rows/block, fused Q LN+RoPE)
    attn_fwd<<<B_*H_*(S_/128), 512, 0, stream>>>(qfb, kr, vt, qnw, cosT, sinT, pids, ao);

    // 5. output projection -> d_out (f32)
    gemm_t<4,0><<<(NROW_/256)*(HID_/256), 512, 0, stream>>>(ao, woT, out, nullptr, NROW_, HID_, H_*D_, HID_/256);
}

// Round 13
// 464.266 us; speedup vs baseline: 1.0017x; 1.0016x over previous
//
#include <hip/hip_runtime.h>
#include <hip/hip_bf16.h>
#include <cstdio>
#include <cstdint>

#define B_    2
#define S_    2048
#define H_    32
#define KVH_  8
#define D_    128
#define HID_  4096
#define WIN_  512
#define NROW_ (B_*S_)          // 4096 rows for projection GEMMs
#define NKV_  2048             // fused k|v output width
#define SCALE_ 0.08838834764831845f          // 128^-0.5
#define SL2E_  0.12751744932973953f          // SCALE_ * log2(e)

typedef __attribute__((ext_vector_type(8))) __bf16 bf16x8;
typedef __attribute__((ext_vector_type(4))) __bf16 bf16x4;
typedef __attribute__((ext_vector_type(4))) float  f32x4;

#define GAS __attribute__((address_space(1)))
#define LAS __attribute__((address_space(3)))

// ------------------------------------------------- merged prep: cvt hidden + 4 weight transposes
__global__ __launch_bounds__(256) void prep_all(const float* __restrict__ hidden,
                                                const float* __restrict__ wq,
                                                const float* __restrict__ wk,
                                                const float* __restrict__ wv,
                                                const float* __restrict__ wo,
                                                __hip_bfloat16* __restrict__ hb,
                                                __hip_bfloat16* __restrict__ wqT,
                                                __hip_bfloat16* __restrict__ wkvT,
                                                __hip_bfloat16* __restrict__ woT) {
    __shared__ float t[32][33];
    const int bid = blockIdx.x;
    if (bid < 16384) {
        const int i = (bid * 256 + threadIdx.x) * 4;
        float4 v = *(const float4*)(hidden + i);
        __hip_bfloat162 a, b;
        a.x = __float2bfloat16(v.x); a.y = __float2bfloat16(v.y);
        b.x = __float2bfloat16(v.z); b.y = __float2bfloat16(v.w);
        *(__hip_bfloat162*)(hb + i)     = a;
        *(__hip_bfloat162*)(hb + i + 2) = b;
        return;
    }
    const int tx = threadIdx.x & 31, ty = threadIdx.x >> 5;
    const int id = bid - 16384;
    const float* src; __hip_bfloat16* dst; int C, idx;   // R always 4096
    if (id < 16384)      { src = wq; dst = wqT;  C = 4096; idx = id; }
    else if (id < 20480) { src = wk; dst = wkvT; C = 1024; idx = id - 16384; }
    else if (id < 24576) { src = wv; dst = wkvT + (size_t)1024*HID_; C = 1024; idx = id - 20480; }
    else                 { src = wo; dst = woT;  C = 4096; idx = id - 24576; }
    const int ctiles = C >> 5;
    const int c0 = (idx % ctiles) * 32, r0 = (idx / ctiles) * 32;
    #pragma unroll
    for (int i = 0; i < 4; ++i)
        t[ty + 8*i][tx] = src[(size_t)(r0 + ty + 8*i) * C + c0 + tx];
    __syncthreads();
    #pragma unroll
    for (int i = 0; i < 4; ++i)
        dst[(size_t)(c0 + ty + 8*i) * HID_ + r0 + tx] = __float2bfloat16(t[tx][ty + 8*i]);
}

// ------------------------------------------------- GEMM 256x256, BK=64, m201-style 8-phase
// A(MxK) bf16 * Bt(NxK)^T.  8 waves (2Mx4N), per-wave C = 128x64.
// LDS 128KB: 2 dbuf x {A 256x64, B 256x64}.  Swizzle: phys_chunk = chunk ^ (row&7)
// (pre-swizzled global src + same XOR on ds_read; linear gload_lds dest — rule 21).
// Per K64-tile, 4 phases = C-quadrants in liveness-minimal order m0n0,m0n1,m1n0,m1n1:
//   {ds_reads ; stage half-tiles(t+1) ; s_barrier ; lgkm(0)+sched_barrier ;
//    setprio(1) 16 MFMA setprio(0) ; s_barrier}
// Stages for t+1 issue at phases 1-2; single vmcnt(0) at phase 4 waits loads ~2-3 phases
// (>=1800cy) old >> HBM latency -> effectively free, never drains fresh loads.
// WAR: stage into dbuf^1 touches tile t-1's buffer, last read before t-1's final barrier.
template <int OMODE>   // 0: f32 out, 1: bf16 out
__global__ __launch_bounds__(512, 2) void gemm8p(const __hip_bfloat16* __restrict__ A,
                                                 const __hip_bfloat16* __restrict__ Bt,
                                                 void* __restrict__ Cv,
                                                 int M, int N, int K, int nbx) {
    __shared__ __align__(16) __hip_bfloat16 L[2][2][256*64];   // [dbuf][A|B][row*64+k]
    const int tid  = threadIdx.x;
    const int lane = tid & 63, w = tid >> 6;
    const int wm = w >> 2, wn = w & 3;                  // 2 x 4 wave grid
    const int lc = lane & 15, lg = lane >> 4;
    const int nwg = gridDim.x, cpx = nwg >> 3;          // XCD-aware bijective swizzle
    const int bid = blockIdx.x;
    const int swz = (bid & 7) * cpx + (bid >> 3);
    const int by = swz / nbx, bx = swz - by * nbx;
    const size_t row0 = (size_t)by * 256, col0 = (size_t)bx * 256;
    const int nt = K >> 6;                              // K64 tiles (even: 64)

    // staging lane constants: per gload instr a wave fills 8 rows x 128B linearly;
    // lane l -> row +(l>>3), phys chunk l&7; global logical chunk = (l&7)^(l>>3).
    const int lrow = lane >> 3;
    const int lchk = (lane & 7) ^ lrow;
    const __hip_bfloat16* Ab = A  + row0 * K;
    const __hip_bfloat16* Bb = Bt + col0 * K;

#define STGH(db_, pl_, half_, kt_) do {                                                   \
    _Pragma("unroll")                                                                     \
    for (int i_ = 0; i_ < 2; ++i_) {                                                      \
        const int rows_ = (half_)*128 + (w*2 + i_)*8;                                     \
        const __hip_bfloat16* gp_ = (pl_) ? Bb : Ab;                                      \
        __builtin_amdgcn_global_load_lds(                                                 \
            (const GAS void*)(gp_ + (size_t)(rows_ + lrow) * K + (size_t)(kt_)*64 + lchk*8), \
            (LAS void*)&L[db_][pl_][rows_*64], 16, 0, 0);                                 \
    }                                                                                     \
} while (0)

#define RDA(db_, mh_) do {                                                                \
    _Pragma("unroll")                                                                     \
    for (int fm = 0; fm < 4; ++fm) {                                                      \
        const int r_ = wm*128 + (mh_)*64 + fm*16 + lc;                                    \
        _Pragma("unroll")                                                                 \
        for (int ks = 0; ks < 2; ++ks)                                                    \
            af[fm][ks] = *(const bf16x8*)&L[db_][0][r_*64 + (((ks*4 + lg) ^ (r_ & 7)) * 8)]; \
    }                                                                                     \
} while (0)

#define RDBN(dst_, db_, nh_) do {                                                         \
    _Pragma("unroll")                                                                     \
    for (int fn = 0; fn < 2; ++fn) {                                                      \
        const int r_ = wn*64 + (nh_)*32 + fn*16 + lc;                                     \
        _Pragma("unroll")                                                                 \
        for (int ks = 0; ks < 2; ++ks)                                                    \
            dst_[fn][ks] = *(const bf16x8*)&L[db_][1][r_*64 + (((ks*4 + lg) ^ (r_ & 7)) * 8)]; \
    }                                                                                     \
} while (0)

#define MMC(mh_, nh_, BF_) do {                                                           \
    __builtin_amdgcn_s_setprio(1);                                                        \
    _Pragma("unroll")                                                                     \
    for (int fm = 0; fm < 4; ++fm)                                                        \
        _Pragma("unroll")                                                                 \
        for (int fn = 0; fn < 2; ++fn)                                                    \
            _Pragma("unroll")                                                             \
            for (int ks = 0; ks < 2; ++ks)                                                \
                acc[mh_][nh_][fm][fn] = __builtin_amdgcn_mfma_f32_16x16x32_bf16(          \
                    af[fm][ks], BF_[fn][ks], acc[mh_][nh_][fm][fn], 0, 0, 0);             \
    __builtin_amdgcn_s_setprio(0);                                                        \
} while (0)

#define BARR() asm volatile("s_barrier" ::: "memory")
#define LGKM0() do { asm volatile("s_waitcnt lgkmcnt(0)" ::: "memory");                   \
                     __builtin_amdgcn_sched_barrier(0); } while (0)

    f32x4 acc[2][2][4][2] = {};
    bf16x8 af[4][2], bn0[2][2], bn1[2][2];

    // prologue: stage tile 0 fully; one exposed drain (once per kernel)
    STGH(0, 0, 0, 0); STGH(0, 0, 1, 0); STGH(0, 1, 0, 0); STGH(0, 1, 1, 0);
    asm volatile("s_waitcnt vmcnt(0)" ::: "memory");
    BARR();

    for (int t = 0; t < nt; ++t) {
        const int db = t & 1, dn = db ^ 1;
        const int tn = (t + 1 < nt) ? (t + 1) : (nt - 1);   // clamped tail (writes dn: safe)

        // P1: quadrant (m0,n0); stage A halves of t+1
        RDA(db, 0); RDBN(bn0, db, 0);
        STGH(dn, 0, 0, tn); STGH(dn, 0, 1, tn);
        BARR(); LGKM0(); MMC(0, 0, bn0); BARR();

        // P2: (m0,n1); stage B halves of t+1
        RDBN(bn1, db, 1);
        STGH(dn, 1, 0, tn); STGH(dn, 1, 1, tn);
        BARR(); LGKM0(); MMC(0, 1, bn1); BARR();

        // P3: (m1,n0)
        RDA(db, 1);
        BARR(); LGKM0(); MMC(1, 0, bn0); BARR();

        // P4: (m1,n1); confirm tile t+1 staged (loads >=2 phases old -> wait ~free)
        asm volatile("s_waitcnt vmcnt(0)" ::: "memory");
        BARR(); MMC(1, 1, bn1); BARR();
    }
#undef STGH
#undef RDA
#undef RDBN
#undef MMC
#undef BARR
#undef LGKM0

    #pragma unroll
    for (int mh = 0; mh < 2; ++mh)
        #pragma unroll
        for (int nh = 0; nh < 2; ++nh)
            #pragma unroll
            for (int fm = 0; fm < 4; ++fm)
                #pragma unroll
                for (int fn = 0; fn < 2; ++fn) {
                    const size_t col = col0 + wn*64 + nh*32 + fn*16 + lc;
                    #pragma unroll
                    for (int rr = 0; rr < 4; ++rr) {
                        const size_t row = row0 + wm*128 + mh*64 + fm*16 + lg*4 + rr;
                        if constexpr (OMODE == 0)
                            ((float*)Cv)[row * N + col] = acc[mh][nh][fm][fn][rr];
                        else
                            ((__hip_bfloat16*)Cv)[row * N + col] =
                                __float2bfloat16(acc[mh][nh][fm][fn][rr]);
                    }
                }
}

// ------------------------------------------------- GEMM 256x128 ring-4 (KV only, R9-proven)
template <int FN, int OMODE>
__global__ __launch_bounds__(512, 2) void gemm_t(const __hip_bfloat16* __restrict__ A,
                                                 const __hip_bfloat16* __restrict__ Bt,
                                                 void* __restrict__ Cv, void* __restrict__ C2,
                                                 int M, int N, int K, int nbx) {
    constexpr int BN   = FN * 64;
    constexpr int BLD  = BN / 128;
    constexpr int SLOT = (256 + BN) * 32;
    __shared__ __align__(16) __hip_bfloat16 L[4 * SLOT];
    const int tid  = threadIdx.x;
    const int lane = tid & 63, w = tid >> 6;
    const int wm = w >> 2, wn = w & 3;
    const int lc = lane & 15, lg = lane >> 4;
    const int nwg = gridDim.x, cpx = nwg >> 3;
    const int bid = blockIdx.x;
    const int swz = (bid & 7) * cpx + (bid >> 3);
    const int by = swz / nbx, bx = swz - by * nbx;
    const size_t row0 = (size_t)by * 256, col0 = (size_t)bx * BN;
    const int nt = K >> 5;

    const int srow = tid >> 2;
    const int spc  = tid & 3;
    const int slx  = spc ^ ((srow >> 1) & 3);
    const __hip_bfloat16* Ab = A  + row0 * K;
    const __hip_bfloat16* Bb = Bt + col0 * K;

#define STGA(tile_) do {                                                                   \
    const int ss_ = (tile_) & 3;                                                           \
    const int kt_ = ((tile_) < nt) ? (tile_) : (nt - 1);                                   \
    _Pragma("unroll")                                                                      \
    for (int rh_ = 0; rh_ < 2; ++rh_)                                                      \
        __builtin_amdgcn_global_load_lds(                                                  \
            (const GAS void*)(Ab + (size_t)(rh_*128 + srow) * K + kt_*32 + slx*8),         \
            (LAS void*)&L[ss_*SLOT + rh_*4096 + w*512], 16, 0, 0);                         \
} while (0)

#define STGB(tile_) do {                                                                   \
    const int ss_ = (tile_) & 3;                                                           \
    const int kt_ = ((tile_) < nt) ? (tile_) : (nt - 1);                                   \
    _Pragma("unroll")                                                                      \
    for (int bh_ = 0; bh_ < BLD; ++bh_)                                                    \
        __builtin_amdgcn_global_load_lds(                                                  \
            (const GAS void*)(Bb + (size_t)(bh_*128 + srow) * K + kt_*32 + slx*8),         \
            (LAS void*)&L[ss_*SLOT + 8192 + bh_*4096 + w*512], 16, 0, 0);                  \
} while (0)

#define VMW2L() do {                                                                       \
    if constexpr (FN == 4) asm volatile("s_waitcnt vmcnt(8)" ::: "memory");                \
    else                   asm volatile("s_waitcnt vmcnt(6)" ::: "memory");                \
} while (0)

    f32x4 acc[2][4][FN] = {};
    bf16x8 afr0[4], afr1[4], bfr[FN];

    STGA(0); STGB(0); STGA(1); STGB(1); STGA(2); STGB(2);
    VMW2L();
    asm volatile("s_barrier" ::: "memory");

    for (int t = 0; t < nt; ++t) {
        const int s_ = t & 3;
        #pragma unroll
        for (int fn = 0; fn < FN; ++fn) {
            const int rB = wn*(FN*16) + fn*16 + lc;
            bfr[fn] = *(const bf16x8*)&L[s_*SLOT + 8192 + rB*32 + ((lg ^ ((rB >> 1) & 3)) * 8)];
        }
        #pragma unroll
        for (int fm = 0; fm < 4; ++fm) {
            const int rA = wm*128 + fm*16 + lc;
            afr0[fm] = *(const bf16x8*)&L[s_*SLOT + rA*32 + ((lg ^ ((rA >> 1) & 3)) * 8)];
        }
        __builtin_amdgcn_sched_barrier(0);
        #pragma unroll
        for (int fm = 0; fm < 4; ++fm) {
            const int rA = wm*128 + 64 + fm*16 + lc;
            afr1[fm] = *(const bf16x8*)&L[s_*SLOT + rA*32 + ((lg ^ ((rA >> 1) & 3)) * 8)];
        }
        STGA(t + 3);
        asm volatile("s_waitcnt lgkmcnt(4)" ::: "memory");
        __builtin_amdgcn_sched_barrier(0);
        __builtin_amdgcn_s_setprio(1);
        #pragma unroll
        for (int fm = 0; fm < 4; ++fm)
            #pragma unroll
            for (int fn = 0; fn < FN; ++fn)
                acc[0][fm][fn] = __builtin_amdgcn_mfma_f32_16x16x32_bf16(
                    afr0[fm], bfr[fn], acc[0][fm][fn], 0, 0, 0);
        __builtin_amdgcn_s_setprio(0);

        STGB(t + 3);
        asm volatile("s_waitcnt lgkmcnt(0)" ::: "memory");
        __builtin_amdgcn_sched_barrier(0);
        __builtin_amdgcn_s_setprio(1);
        #pragma unroll
        for (int fm = 0; fm < 4; ++fm)
            #pragma unroll
            for (int fn = 0; fn < FN; ++fn)
                acc[1][fm][fn] = __builtin_amdgcn_mfma_f32_16x16x32_bf16(
                    afr1[fm], bfr[fn], acc[1][fm][fn], 0, 0, 0);
        __builtin_amdgcn_s_setprio(0);
        VMW2L();
        asm volatile("s_barrier" ::: "memory");
    }
#undef STGA
#undef STGB
#undef VMW2L
    asm volatile("s_waitcnt vmcnt(0)" ::: "memory");

    if constexpr (OMODE == 2) {                         // KV split (FN==2, BN=128)
        if (bx < 8) {                                   // K columns -> kf bf16, LD 1024
            __hip_bfloat16* C = (__hip_bfloat16*)Cv;
            #pragma unroll
            for (int qm = 0; qm < 2; ++qm)
                #pragma unroll
                for (int fm = 0; fm < 4; ++fm)
                    #pragma unroll
                    for (int fn = 0; fn < FN; ++fn) {
                        const size_t col = col0 + wn*32 + fn*16 + lc;
                        #pragma unroll
                        for (int rr = 0; rr < 4; ++rr) {
                            const size_t row = row0 + wm*128 + qm*64 + fm*16 + lg*4 + rr;
                            C[row * 1024 + col] = __float2bfloat16(acc[qm][fm][fn][rr]);
                        }
                    }
        } else {                                        // V columns -> vt (B,KVH,D,S) via LDS
            __hip_bfloat16* lt = (__hip_bfloat16*)L;    // [128 d][264 pad]
            __syncthreads();
            #pragma unroll
            for (int qm = 0; qm < 2; ++qm)
                #pragma unroll
                for (int fm = 0; fm < 4; ++fm)
                    #pragma unroll
                    for (int fn = 0; fn < FN; ++fn) {
                        const int cl = wn*32 + fn*16 + lc;
                        #pragma unroll
                        for (int rr = 0; rr < 4; ++rr) {
                            const int rl = wm*128 + qm*64 + fm*16 + lg*4 + rr;
                            lt[cl*264 + rl] = __float2bfloat16(acc[qm][fm][fn][rr]);
                        }
                    }
            __syncthreads();
            const int bb = (int)(row0 >> 11), s0 = (int)(row0 & 2047);
            const int g  = (int)((col0 - 1024) >> 7);
            __hip_bfloat16* vto = (__hip_bfloat16*)C2 + (((size_t)bb*KVH_ + g) * D_) * (size_t)S_;
            const int d = tid >> 2, sc0 = (tid & 3) * 64;
            #pragma unroll
            for (int j = 0; j < 64; j += 8) {
                bf16x8 v = *(const bf16x8*)&lt[d*264 + sc0 + j];
                *(bf16x8*)&vto[(size_t)d*S_ + s0 + sc0 + j] = v;
            }
        }
    }
}

// ------------------------------------------------- per-head LN + interleaved RoPE (bf16 in)
// used only for K.  in: x (B*S, LD) bf16.  out: (B, NH, S, D) bf16.
template <int NH, int LD, int XOFF>
__global__ __launch_bounds__(256) void ln_rope(const __hip_bfloat16* __restrict__ x,
                                               const float* __restrict__ wln,
                                               const float* __restrict__ cosT,
                                               const float* __restrict__ sinT,
                                               const int* __restrict__ pids,
                                               __hip_bfloat16* __restrict__ out) {
    const int lane = threadIdx.x & 63, wv = threadIdx.x >> 6;
    const int r = blockIdx.x * 4 + wv;
    const int h = r % NH;
    const int bs = r / NH;
    const int b = bs / S_, s = bs % S_;
    const __hip_bfloat162 xv2 = *(const __hip_bfloat162*)(x + (size_t)bs * LD + XOFF + h*D_ + lane*2);
    const float x0 = __bfloat162float(xv2.x), x1 = __bfloat162float(xv2.y);
    float sum = x0 + x1;
    #pragma unroll
    for (int o = 32; o; o >>= 1) sum += __shfl_xor(sum, o);
    const float mu = sum * (1.f / D_);
    const float dx = x0 - mu, dy = x1 - mu;
    float vs = dx*dx + dy*dy;
    #pragma unroll
    for (int o = 32; o; o >>= 1) vs += __shfl_xor(vs, o);
    const float rs = rsqrtf(vs * (1.f / D_) + 1e-5f);
    const float2 w2 = *(const float2*)(wln + lane*2);
    const float y0 = w2.x * dx * rs, y1 = w2.y * dy * rs;
    const int p = pids[bs];
    const float2 c  = *(const float2*)(cosT + (size_t)p * D_ + lane*2);
    const float2 sn = *(const float2*)(sinT + (size_t)p * D_ + lane*2);
    __hip_bfloat162 ov;
    ov.x = __float2bfloat16(y0 * c.x - y1 * sn.x);
    ov.y = __float2bfloat16(y1 * c.y + y0 * sn.y);
    *(__hip_bfloat162*)(out + (((size_t)b * NH + h) * S_ + s) * D_ + lane*2) = ov;
}

// chunk swizzle for attn K tile (16B chunks, 16/row)
static __device__ __forceinline__ int sigk_(int r) { return (r & 3) | ((r >> 1) & 4); }

// ------------------------------------------------- sliding-window GQA flash attention v4
// (unchanged from R10 — 8 waves / 128 q-rows, fused Q LN+RoPE, counted vmcnt staging)
__global__ __launch_bounds__(512, 4) void attn_fwd(const __hip_bfloat16* __restrict__ qfb,
                                                   const __hip_bfloat16* __restrict__ kr,
                                                   const __hip_bfloat16* __restrict__ vt,
                                                   const float* __restrict__ qnw,
                                                   const float* __restrict__ cosT,
                                                   const float* __restrict__ sinT,
                                                   const int* __restrict__ pids,
                                                   __hip_bfloat16* __restrict__ ao) {
    __shared__ __align__(16) __hip_bfloat16 Ksl[2][64*D_];    // 2 x 16KB
    __shared__ __align__(16) __hip_bfloat16 Vsl[2][D_*64];    // 2 x 16KB
    const int tid = threadIdx.x;
    const int lane = tid & 63, w = tid >> 6;     // 8 waves
    const int lq = lane & 15, lg = lane >> 4;
    const int blk = blockIdx.x;
    const int qt = blk & 15;
    const int bh = blk >> 4;
    const int h = bh & (H_-1), b = bh >> 5;
    const int g = h >> 2;
    const int q0 = qt*128 + w*16;
    const int q  = q0 + lq;

    const __hip_bfloat16* kbase = kr + ((size_t)b*KVH_ + g) * (size_t)S_ * D_;
    const __hip_bfloat16* vbase = vt + ((size_t)b*KVH_ + g) * (size_t)D_ * S_;

    const int srK = lane >> 4, scK = lane & 15;
    const int srV = lane >> 3, scV = lane & 7;

#define STAGE(nb, k0s) do {                                                              \
    _Pragma("unroll")                                                                    \
    for (int s_ = 0; s_ < 2; ++s_) {                                                     \
        const int rK_ = w*8 + s_*4 + srK;                                                \
        const __hip_bfloat16* srcK_ = kbase + (size_t)((k0s) + rK_)*D_                   \
                                      + ((scK ^ sigk_(rK_)) * 8);                        \
        __builtin_amdgcn_global_load_lds((const GAS void*)srcK_,                         \
            (LAS void*)&Ksl[nb][(w*8 + s_*4)*D_], 16, 0, 0);                             \
    }                                                                                    \
    _Pragma("unroll")                                                                    \
    for (int s_ = 0; s_ < 2; ++s_) {                                                     \
        const int dV_ = w*16 + s_*8 + srV;                                               \
        const __hip_bfloat16* srcV_ = vbase + (size_t)dV_*S_ + (k0s)                     \
                                      + ((scV ^ (dV_ & 7)) * 8);                         \
        __builtin_amdgcn_global_load_lds((const GAS void*)srcV_,                         \
            (LAS void*)&Vsl[nb][(w*16 + s_*8)*64], 16, 0, 0);                            \
    }                                                                                    \
} while (0)

    int kst = qt*128 - (WIN_ - 1); if (kst < 0) kst = 0; kst &= ~63;
    const int nt = qt*2 + 2 - (kst >> 6);

    union { bf16x8 v; __hip_bfloat16 e[8]; } qraw[4];
    const __hip_bfloat16* qb2 = qfb + ((size_t)(b*S_ + q)) * HID_ + h*D_;
    #pragma unroll
    for (int kk = 0; kk < 4; ++kk)
        qraw[kk].v = *(const bf16x8*)(qb2 + kk*32 + lg*8);
    const int p = pids[b*S_ + q];

    STAGE(0, kst);

    float sum = 0.f;
    #pragma unroll
    for (int kk = 0; kk < 4; ++kk)
        #pragma unroll
        for (int j = 0; j < 8; ++j) sum += __bfloat162float(qraw[kk].e[j]);
    sum += __shfl_xor(sum, 16); sum += __shfl_xor(sum, 32);
    const float mu = sum * (1.f / D_);
    float vsq = 0.f;
    #pragma unroll
    for (int kk = 0; kk < 4; ++kk)
        #pragma unroll
        for (int j = 0; j < 8; ++j) {
            const float dxx = __bfloat162float(qraw[kk].e[j]) - mu;
            vsq += dxx * dxx;
        }
    vsq += __shfl_xor(vsq, 16); vsq += __shfl_xor(vsq, 32);
    const float rsq = rsqrtf(vsq * (1.f / D_) + 1e-5f);

    bf16x8 qf[4];
    #pragma unroll
    for (int kk = 0; kk < 4; ++kk) {
        const int d0 = kk*32 + lg*8;
        float wl[8], cc[8], ss[8], y[8];
        *(float4*)&wl[0] = *(const float4*)(qnw + d0);
        *(float4*)&wl[4] = *(const float4*)(qnw + d0 + 4);
        *(float4*)&cc[0] = *(const float4*)(cosT + (size_t)p*D_ + d0);
        *(float4*)&cc[4] = *(const float4*)(cosT + (size_t)p*D_ + d0 + 4);
        *(float4*)&ss[0] = *(const float4*)(sinT + (size_t)p*D_ + d0);
        *(float4*)&ss[4] = *(const float4*)(sinT + (size_t)p*D_ + d0 + 4);
        #pragma unroll
        for (int j = 0; j < 8; ++j)
            y[j] = wl[j] * (__bfloat162float(qraw[kk].e[j]) - mu) * rsq;
        union { bf16x8 v; __hip_bfloat16 e[8]; } qo;
        #pragma unroll
        for (int mpair = 0; mpair < 4; ++mpair) {
            qo.e[2*mpair]   = __float2bfloat16(y[2*mpair]   * cc[2*mpair]   - y[2*mpair+1] * ss[2*mpair]);
            qo.e[2*mpair+1] = __float2bfloat16(y[2*mpair+1] * cc[2*mpair+1] + y[2*mpair]   * ss[2*mpair+1]);
        }
        qf[kk] = qo.v;
    }

    f32x4 o[8] = {};
    float m = -1e30f, l = 0.f;
    const int kldrow = 8*(lq >> 2) + (lq & 3);

    for (int t = 0; t < nt; ++t) {
        const int k0 = kst + t*64;
        const int buf = t & 1;
        if (t + 1 < nt) {
            STAGE((t + 1) & 1, k0 + 64);
            asm volatile("s_waitcnt vmcnt(4)" ::: "memory");
        } else {
            asm volatile("s_waitcnt vmcnt(0)" ::: "memory");
        }
        __builtin_amdgcn_s_barrier();

        f32x4 sc[2][2] = {};
        __builtin_amdgcn_s_setprio(1);
        #pragma unroll
        for (int kb = 0; kb < 2; ++kb)
            #pragma unroll
            for (int f = 0; f < 2; ++f) {
                const int rA = kb*32 + 4*f + kldrow;
                const __hip_bfloat16* kp = &Ksl[buf][rA*D_];
                #pragma unroll
                for (int kk = 0; kk < 4; ++kk) {
                    bf16x8 ka = *(const bf16x8*)(kp + (((kk*4 + lg) ^ sigk_(rA)) * 8));
                    sc[kb][f] = __builtin_amdgcn_mfma_f32_16x16x32_bf16(ka, qf[kk], sc[kb][f], 0, 0, 0);
                }
            }
        __builtin_amdgcn_s_setprio(0);

        const int dqk = q - (k0 + 8*lg);
        float pv[16];
        float mx = -INFINITY;
        #pragma unroll
        for (int kb = 0; kb < 2; ++kb)
            #pragma unroll
            for (int f = 0; f < 2; ++f)
                #pragma unroll
                for (int r = 0; r < 4; ++r) {
                    const int c = kb*32 + 4*f + r;
                    const int d = dqk - c;
                    float v = (d >= 0 && d < WIN_) ? sc[kb][f][r] * SL2E_ : -INFINITY;
                    pv[kb*8 + f*4 + r] = v;
                    mx = fmaxf(mx, v);
                }
        mx = fmaxf(mx, __shfl_xor(mx, 16));
        mx = fmaxf(mx, __shfl_xor(mx, 32));
        const float mn = fmaxf(m, mx);
        const float alpha = exp2f(m - mn);
        float ls = 0.f;
        union { bf16x8 v; __hip_bfloat16 e[8]; } pu[2];
        #pragma unroll
        for (int kb = 0; kb < 2; ++kb)
            #pragma unroll
            for (int j = 0; j < 8; ++j) {
                const float pw = exp2f(pv[kb*8 + j] - mn);
                ls += pw;
                pu[kb].e[j] = __float2bfloat16(pw);
            }
        ls += __shfl_xor(ls, 16);
        ls += __shfl_xor(ls, 32);
        l = l * alpha + ls;
        m = mn;
        #pragma unroll
        for (int n = 0; n < 8; ++n) {
            o[n][0] *= alpha; o[n][1] *= alpha; o[n][2] *= alpha; o[n][3] *= alpha;
        }

        __builtin_amdgcn_s_setprio(1);
        #pragma unroll
        for (int kb = 0; kb < 2; ++kb)
            #pragma unroll
            for (int n = 0; n < 8; ++n) {
                const int dR = n*16 + lq;
                bf16x8 vf8 = *(const bf16x8*)(&Vsl[buf][dR*64] + (((kb*4 + lg) ^ (dR & 7)) * 8));
                o[n] = __builtin_amdgcn_mfma_f32_16x16x32_bf16(vf8, pu[kb].v, o[n], 0, 0, 0);
            }
        __builtin_amdgcn_s_setprio(0);

        if (t + 1 < nt) __builtin_amdgcn_s_barrier();
    }
#undef STAGE

    const float rinv = 1.f / l;
    #pragma unroll
    for (int n = 0; n < 8; ++n) {
        union { bf16x4 v; __hip_bfloat16 e[4]; } ov;
        #pragma unroll
        for (int r = 0; r < 4; ++r) ov.e[r] = __float2bfloat16(o[n][r] * rinv);
        *(bf16x4*)(ao + ((size_t)b*S_ + q)*(H_*D_) + h*D_ + n*16 + lg*4) = ov.v;
    }
}

// ----------------------------------------------------------------- host
extern "C" void kernel_launch(void* const* d_in, const int* in_sizes, int n_in,
                              void* d_out, int out_size, void* d_ws, size_t ws_size,
                              hipStream_t stream) {
    const float* hidden = (const float*)d_in[0];
    const int*   pids   = (const int*)  d_in[1];
    const float* cosT   = (const float*)d_in[2];
    const float* sinT   = (const float*)d_in[3];
    const float* wq     = (const float*)d_in[4];
    const float* wk     = (const float*)d_in[5];
    const float* wv     = (const float*)d_in[6];
    const float* wo     = (const float*)d_in[7];
    const float* qnw    = (const float*)d_in[8];
    const float* knw    = (const float*)d_in[9];
    float* out = (float*)d_out;

    char* base = (char*)d_ws;
    size_t off = 0;
    auto take = [&](size_t bytes) -> void* {
        void* q = base + off;
        off = (off + bytes + 255) & ~(size_t)255;
        return q;
    };
    __hip_bfloat16* qfb  = (__hip_bfloat16*)take((size_t)NROW_*HID_*2);   // Q proj bf16
    __hip_bfloat16* ao   = (__hip_bfloat16*)take((size_t)NROW_*HID_*2);   // attn out bf16
    __hip_bfloat16* kf   = (__hip_bfloat16*)take((size_t)NROW_*1024*2);   // K proj bf16
    __hip_bfloat16* hb   = (__hip_bfloat16*)take((size_t)NROW_*HID_*2);
    __hip_bfloat16* wqT  = (__hip_bfloat16*)take((size_t)HID_*HID_*2);
    __hip_bfloat16* wkvT = (__hip_bfloat16*)take((size_t)NKV_*HID_*2);
    __hip_bfloat16* woT  = (__hip_bfloat16*)take((size_t)HID_*HID_*2);
    __hip_bfloat16* kr   = (__hip_bfloat16*)take((size_t)B_*KVH_*S_*D_*2);
    __hip_bfloat16* vt   = (__hip_bfloat16*)take((size_t)B_*KVH_*S_*D_*2);

    if (off > ws_size) {
        fprintf(stderr, "WORKSPACE TOO SMALL: need %zu have %zu\n", off, ws_size);
        return;
    }

    // 1. merged prep: hidden convert + 4 weight transposes (1 launch)
    prep_all<<<16384 + 40960, 256, 0, stream>>>(hidden, wq, wk, wv, wo, hb, wqT, wkvT, woT);

    // 2. projections — every grid exactly 256 blocks (1 round on 256 CUs)
    gemm8p<1><<<(NROW_/256)*(HID_/256), 512, 0, stream>>>(hb, wqT, qfb, NROW_, HID_, HID_, HID_/256);
    gemm_t<2,2><<<(NROW_/256)*(NKV_/128), 512, 0, stream>>>(hb, wkvT, kf, vt, NROW_, NKV_, HID_, NKV_/128);

    // 3. LN + RoPE for K only (Q is fused into attention)
    ln_rope<KVH_, 1024, 0><<<(B_*S_*KVH_)/4, 256, 0, stream>>>(kf, knw, cosT, sinT, pids, kr);

    // 4. attention (8 waves, 128 q-rows/block, fused Q LN+RoPE)
    attn_fwd<<<B_*H_*(S_/128), 512, 0, stream>>>(qfb, kr, vt, qnw, cosT, sinT, pids, ao);

    // 5. output projection -> d_out (f32)
    gemm8p<0><<<(NROW_/256)*(HID_/256), 512, 0, stream>>>(ao, woT, out, NROW_, HID_, H_*D_, HID_/256);
}